// Round 7
// baseline (8871.997 us; speedup 1.0000x reference)
//
#include <hip/hip_runtime.h>

#define NDIM 2048
#define KDIM 4096
#define NN (NDIM * NDIM)

// ==================== big NT GEMM: C[2048][2048] = A(2048x4096)*B(2048x4096)^T
// 128x128 tile, BK=16, 512 threads, 8x4 per thread, dbuf LDS. (measured 494us)
__global__ __launch_bounds__(512) void gemm_nt_big(const float* __restrict__ A,
                                                   const float* __restrict__ B,
                                                   float* __restrict__ C) {
  __shared__ float As[2][16][128];
  __shared__ float Bs[2][16][128];
  const int t = threadIdx.x;
  const int tx = t & 31;
  const int ty = t >> 5;
  const int lr = t >> 2;
  const int lk = (t & 3) * 4;
  const float* Ap = A + (size_t)(blockIdx.y * 128 + lr) * KDIM + lk;
  const float* Bp = B + (size_t)(blockIdx.x * 128 + lr) * KDIM + lk;
  float acc[8][4];
#pragma unroll
  for (int r = 0; r < 8; ++r)
#pragma unroll
    for (int c = 0; c < 4; ++c) acc[r][c] = 0.f;
  {
    float4 a = *(const float4*)Ap;
    float4 b = *(const float4*)Bp;
    As[0][lk + 0][lr] = a.x; As[0][lk + 1][lr] = a.y;
    As[0][lk + 2][lr] = a.z; As[0][lk + 3][lr] = a.w;
    Bs[0][lk + 0][lr] = b.x; Bs[0][lk + 1][lr] = b.y;
    Bs[0][lk + 2][lr] = b.z; Bs[0][lk + 3][lr] = b.w;
  }
  int cur = 0;
  for (int k0 = 16;; k0 += 16) {
    const bool more = k0 < KDIM;
    float4 na, nb;
    if (more) {
      na = *(const float4*)(Ap + k0);
      nb = *(const float4*)(Bp + k0);
    }
    __syncthreads();
#pragma unroll
    for (int kk = 0; kk < 16; ++kk) {
      float ra[8], rb[4];
#pragma unroll
      for (int r = 0; r < 8; ++r) ra[r] = As[cur][kk][ty * 8 + r];
#pragma unroll
      for (int c = 0; c < 4; ++c) rb[c] = Bs[cur][kk][tx * 4 + c];
#pragma unroll
      for (int r = 0; r < 8; ++r)
#pragma unroll
        for (int c = 0; c < 4; ++c) acc[r][c] += ra[r] * rb[c];
    }
    if (!more) break;
    const int nx = cur ^ 1;
    As[nx][lk + 0][lr] = na.x; As[nx][lk + 1][lr] = na.y;
    As[nx][lk + 2][lr] = na.z; As[nx][lk + 3][lr] = na.w;
    Bs[nx][lk + 0][lr] = nb.x; Bs[nx][lk + 1][lr] = nb.y;
    Bs[nx][lk + 2][lr] = nb.z; Bs[nx][lk + 3][lr] = nb.w;
    cur = nx;
  }
#pragma unroll
  for (int r = 0; r < 8; ++r) {
    float* p = C + (size_t)(blockIdx.y * 128 + ty * 8 + r) * NDIM + blockIdx.x * 128 + tx * 4;
    float4 v = {acc[r][0], acc[r][1], acc[r][2], acc[r][3]};
    *(float4*)p = v;
  }
}

// ==================== generic 64x64 tile GEMM (finals) ====================
template <bool TA>
__global__ __launch_bounds__(256) void gemm_tile64(const float* __restrict__ A,
                                                   const float* __restrict__ B,
                                                   float* C, int M, int N, int K,
                                                   int lda, int ldb, int ldc,
                                                   float alpha, float beta) {
  __shared__ float As[16][64];
  __shared__ float Bs[16][64];
  const int t = threadIdx.x;
  const int tx = t & 15, ty = t >> 4;
  const int i0 = blockIdx.y * 64, j0 = blockIdx.x * 64;
  float acc[4][4];
#pragma unroll
  for (int r = 0; r < 4; ++r)
#pragma unroll
    for (int c = 0; c < 4; ++c) acc[r][c] = 0.f;

  for (int k0 = 0; k0 < K; k0 += 16) {
    float4 av, bv;
    if (TA) {
      av = *(const float4*)(A + (size_t)(k0 + ty) * lda + i0 + tx * 4);
    } else {
      av = *(const float4*)(A + (size_t)(i0 + (t >> 2)) * lda + k0 + (t & 3) * 4);
    }
    bv = *(const float4*)(B + (size_t)(k0 + ty) * ldb + j0 + tx * 4);
    __syncthreads();
    if (TA) {
      *(float4*)&As[ty][tx * 4] = av;
    } else {
      const int i = t >> 2, k4 = (t & 3) * 4;
      As[k4 + 0][i] = av.x; As[k4 + 1][i] = av.y;
      As[k4 + 2][i] = av.z; As[k4 + 3][i] = av.w;
    }
    *(float4*)&Bs[ty][tx * 4] = bv;
    __syncthreads();
#pragma unroll
    for (int kk = 0; kk < 16; ++kk) {
      float ra[4], rb[4];
#pragma unroll
      for (int r = 0; r < 4; ++r) ra[r] = As[kk][ty * 4 + r];
#pragma unroll
      for (int c = 0; c < 4; ++c) rb[c] = Bs[kk][tx * 4 + c];
#pragma unroll
      for (int r = 0; r < 4; ++r)
#pragma unroll
        for (int c = 0; c < 4; ++c) acc[r][c] += ra[r] * rb[c];
    }
  }
#pragma unroll
  for (int r = 0; r < 4; ++r) {
    float* p = C + (size_t)(i0 + ty * 4 + r) * ldc + j0 + tx * 4;
    float4 old = *(const float4*)p;
    float4 v;
    v.x = alpha * acc[r][0] + beta * old.x;
    v.y = alpha * acc[r][1] + beta * old.y;
    v.z = alpha * acc[r][2] + beta * old.z;
    v.w = alpha * acc[r][3] + beta * old.w;
    *(float4*)p = v;
  }
}

// ==================== E = 0.5*(E + P) + 0.5*(R - R^T) =====================
__global__ __launch_bounds__(256) void make_E(float* E, const float* __restrict__ P,
                                              const float* __restrict__ R) {
  __shared__ float Rt[64][65];
  const int bi = blockIdx.y, bj = blockIdx.x;
  const int t = threadIdx.x;
  for (int idx = t; idx < 4096; idx += 256) {
    int r = idx >> 6, c = idx & 63;
    Rt[r][c] = R[(size_t)(bj * 64 + r) * NDIM + bi * 64 + c];
  }
  __syncthreads();
  for (int idx = t; idx < 4096; idx += 256) {
    int r = idx >> 6, c = idx & 63;
    size_t off = (size_t)(bi * 64 + r) * NDIM + bj * 64 + c;
    E[off] = 0.5f * (E[off] + P[off]) + 0.5f * (R[off] - Rt[c][r]);
  }
}

// ==================== in-LDS LU of a 128x128 tile (512 threads) ===========
__device__ __forceinline__ void lu128_inlds(float* __restrict__ S, int t) {
  const int row = t & 127, cw = t >> 7;  // 4 column workers per row
  for (int j = 0; j < 127; ++j) {
    const float rp = 1.0f / S[j * 129 + j];
    if (cw == 0 && row > j) S[row * 129 + j] *= rp;
    __syncthreads();
    if (row > j) {
      const float lv = S[row * 129 + j];
      for (int c = j + 1 + cw; c < 128; c += 4) S[row * 129 + c] -= lv * S[j * 129 + c];
    }
    __syncthreads();
  }
}

__global__ __launch_bounds__(512) void lu_diag128(float* __restrict__ E, int k) {
  __shared__ float S[128 * 129];
  const int t = threadIdx.x;
  for (int idx = t; idx < 16384; idx += 512)
    S[(idx >> 7) * 129 + (idx & 127)] = E[(size_t)(k + (idx >> 7)) * NDIM + k + (idx & 127)];
  __syncthreads();
  lu128_inlds(S, t);
  for (int idx = t; idx < 16384; idx += 512)
    E[(size_t)(k + (idx >> 7)) * NDIM + k + (idx & 127)] = S[(idx >> 7) * 129 + (idx & 127)];
}

// ==================== triangular inverses of the 128-diag block ===========
__device__ __forceinline__ void load64b(float* __restrict__ dst, const float* __restrict__ E,
                                        int r0, int c0, int t) {
  for (int idx = t; idx < 4096; idx += 256)
    dst[(idx >> 6) * 65 + (idx & 63)] = E[(size_t)(r0 + (idx >> 6)) * NDIM + c0 + (idx & 63)];
}
// column c of inv(unit-lower S) -> D  (all register indices static)
__device__ __forceinline__ void lo_inv_col(const float* __restrict__ S, float* __restrict__ D, int c) {
  float x[64];
#pragma unroll
  for (int i = 0; i < 64; ++i) {
    float s = 0.f;
#pragma unroll
    for (int k2 = 0; k2 < 64; ++k2)
      if (k2 < i) s += S[i * 65 + k2] * x[k2];
    x[i] = (i < c) ? 0.f : ((i == c ? 1.f : 0.f) - s);
  }
#pragma unroll
  for (int i = 0; i < 64; ++i) D[i * 65 + c] = x[i];
}
// column c of inv(upper S) -> D
__device__ __forceinline__ void up_inv_col(const float* __restrict__ S, float* __restrict__ D, int c) {
  float x[64];
#pragma unroll
  for (int ii = 0; ii < 64; ++ii) {
    const int i = 63 - ii;
    float s = 0.f;
#pragma unroll
    for (int k2 = 0; k2 < 64; ++k2)
      if (k2 > i) s += S[i * 65 + k2] * x[k2];
    x[i] = (i > c) ? 0.f : ((i == c ? 1.f : 0.f) - s) / S[i * 65 + i];
  }
#pragma unroll
  for (int i = 0; i < 64; ++i) D[i * 65 + c] = x[i];
}
// C(lds,65) = sgn * A(64x64,65)*B(64x64,65), 256 threads
__device__ __forceinline__ void mm64(const float* __restrict__ A, const float* __restrict__ B,
                                     float* __restrict__ C, int t, float sgn) {
  const int tr = t >> 4, tc = t & 15;
  float acc[4][4];
#pragma unroll
  for (int r = 0; r < 4; ++r)
#pragma unroll
    for (int c = 0; c < 4; ++c) acc[r][c] = 0.f;
  for (int k2 = 0; k2 < 64; ++k2) {
    float ra[4], rb[4];
#pragma unroll
    for (int r = 0; r < 4; ++r) ra[r] = A[(tr * 4 + r) * 65 + k2];
#pragma unroll
    for (int c = 0; c < 4; ++c) rb[c] = B[k2 * 65 + tc * 4 + c];
#pragma unroll
    for (int r = 0; r < 4; ++r)
#pragma unroll
      for (int c = 0; c < 4; ++c) acc[r][c] += ra[r] * rb[c];
  }
#pragma unroll
  for (int r = 0; r < 4; ++r)
#pragma unroll
    for (int c = 0; c < 4; ++c) C[(tr * 4 + r) * 65 + tc * 4 + c] = sgn * acc[r][c];
}
// same but dst = global row-major ld 128
__device__ __forceinline__ void mm64g(const float* __restrict__ A, const float* __restrict__ B,
                                      float* __restrict__ G, int t, float sgn) {
  const int tr = t >> 4, tc = t & 15;
  float acc[4][4];
#pragma unroll
  for (int r = 0; r < 4; ++r)
#pragma unroll
    for (int c = 0; c < 4; ++c) acc[r][c] = 0.f;
  for (int k2 = 0; k2 < 64; ++k2) {
    float ra[4], rb[4];
#pragma unroll
    for (int r = 0; r < 4; ++r) ra[r] = A[(tr * 4 + r) * 65 + k2];
#pragma unroll
    for (int c = 0; c < 4; ++c) rb[c] = B[k2 * 65 + tc * 4 + c];
#pragma unroll
    for (int r = 0; r < 4; ++r)
#pragma unroll
      for (int c = 0; c < 4; ++c) acc[r][c] += ra[r] * rb[c];
  }
#pragma unroll
  for (int r = 0; r < 4; ++r)
#pragma unroll
    for (int c = 0; c < 4; ++c) G[(tr * 4 + r) * 128 + tc * 4 + c] = sgn * acc[r][c];
}

// Lo/Uo: dense 128x128 inverses of the unit-lower / upper factors at E[k][k].
__global__ __launch_bounds__(256) void tri_inv128(const float* __restrict__ E, int k,
                                                  float* __restrict__ Lo,
                                                  float* __restrict__ Uo) {
  __shared__ float s0[4160], s1[4160], s2[4160], s3[4160];
  const int t = threadIdx.x;
  // ---- U side ----
  load64b(s0, E, k, k, t);             // U11
  load64b(s1, E, k + 64, k + 64, t);   // U22
  __syncthreads();
  if (t < 64) up_inv_col(s0, s2, t);
  else if (t < 128) up_inv_col(s1, s3, t - 64);
  __syncthreads();
  load64b(s0, E, k, k + 64, t);        // U12 (U11 dead)
  __syncthreads();
  mm64(s0, s3, s1, t, 1.f);            // s1 = U12 * U22inv (U22 dead)
  __syncthreads();
  mm64g(s2, s1, Uo + 64, t, -1.f);     // Uo[0:64][64:128] = -U11inv*(U12*U22inv)
  for (int idx = t; idx < 4096; idx += 256) {
    const int r = idx >> 6, c = idx & 63;
    Uo[r * 128 + c] = s2[r * 65 + c];
    Uo[(64 + r) * 128 + 64 + c] = s3[r * 65 + c];
    Uo[(64 + r) * 128 + c] = 0.f;
  }
  __syncthreads();
  // ---- L side ----
  load64b(s0, E, k, k, t);             // L11 (unit diag implied; only k2<i read)
  load64b(s1, E, k + 64, k + 64, t);   // L22
  __syncthreads();
  if (t < 64) lo_inv_col(s0, s2, t);
  else if (t < 128) lo_inv_col(s1, s3, t - 64);
  __syncthreads();
  load64b(s0, E, k + 64, k, t);        // L21
  __syncthreads();
  mm64(s0, s2, s1, t, 1.f);            // s1 = L21 * L11inv
  __syncthreads();
  mm64g(s3, s1, Lo + 64 * 128, t, -1.f);  // Lo[64:128][0:64]
  for (int idx = t; idx < 4096; idx += 256) {
    const int r = idx >> 6, c = idx & 63;
    Lo[r * 128 + c] = s2[r * 65 + c];
    Lo[(64 + r) * 128 + 64 + c] = s3[r * 65 + c];
    Lo[r * 128 + 64 + c] = 0.f;
  }
}

// ==================== LU panels via diag inverses (plain GEMM, in place) ==
// blocks [0,nb): L21 rows (64-row slabs): A21(64x128)*Uinv -> same place.
// blocks [nb,2nb): U12 cols (64-col stripes): Linv*A12(128x64) -> same place.
__global__ __launch_bounds__(256) void lu_panels_inv(float* __restrict__ E, int k,
                                                     const float* __restrict__ Li,
                                                     const float* __restrict__ Ui,
                                                     int nb) {
  __shared__ float sh[3072];
  const int t = threadIdx.x;
  if ((int)blockIdx.x < nb) {
    float* As2 = sh;          // [16][64]
    float* Bs = sh + 1024;    // [16][128]
    const int r0 = k + 128 + (int)blockIdx.x * 64;
    const int ty = t >> 5, tx = t & 31;  // 8 rows x 4 cols per thread
    const int lr = t >> 2, k4 = (t & 3) * 4;
    const int kk = t >> 4, c8 = (t & 15) * 8;
    float acc[8][4];
#pragma unroll
    for (int r = 0; r < 8; ++r)
#pragma unroll
      for (int c = 0; c < 4; ++c) acc[r][c] = 0.f;
    for (int kb = 0; kb < 128; kb += 16) {
      float4 av = *(const float4*)(E + (size_t)(r0 + lr) * NDIM + k + kb + k4);
      float4 u0 = *(const float4*)(Ui + (kb + kk) * 128 + c8);
      float4 u1 = *(const float4*)(Ui + (kb + kk) * 128 + c8 + 4);
      __syncthreads();
      As2[(k4 + 0) * 64 + lr] = av.x; As2[(k4 + 1) * 64 + lr] = av.y;
      As2[(k4 + 2) * 64 + lr] = av.z; As2[(k4 + 3) * 64 + lr] = av.w;
      *(float4*)&Bs[kk * 128 + c8] = u0;
      *(float4*)&Bs[kk * 128 + c8 + 4] = u1;
      __syncthreads();
#pragma unroll
      for (int k2 = 0; k2 < 16; ++k2) {
        float ra[8], rb[4];
#pragma unroll
        for (int r = 0; r < 8; ++r) ra[r] = As2[k2 * 64 + ty * 8 + r];
#pragma unroll
        for (int c = 0; c < 4; ++c) rb[c] = Bs[k2 * 128 + tx * 4 + c];
#pragma unroll
        for (int r = 0; r < 8; ++r)
#pragma unroll
          for (int c = 0; c < 4; ++c) acc[r][c] += ra[r] * rb[c];
      }
    }
#pragma unroll
    for (int r = 0; r < 8; ++r) {
      float4 v = {acc[r][0], acc[r][1], acc[r][2], acc[r][3]};
      *(float4*)(E + (size_t)(r0 + ty * 8 + r) * NDIM + k + tx * 4) = v;
    }
  } else {
    float* Ls = sh;           // [16][128]
    float* Cs = sh + 2048;    // [16][64]
    const int c0 = k + 128 + ((int)blockIdx.x - nb) * 64;
    const int ty = t >> 4, tx = t & 15;  // 8 rows x 4 cols per thread
    const int lr = t >> 1, k8 = (t & 1) * 8;
    const int kk = t >> 4, c4 = (t & 15) * 4;
    float acc[8][4];
#pragma unroll
    for (int r = 0; r < 8; ++r)
#pragma unroll
      for (int c = 0; c < 4; ++c) acc[r][c] = 0.f;
    for (int kb = 0; kb < 128; kb += 16) {
      float4 l0 = *(const float4*)(Li + lr * 128 + kb + k8);
      float4 l1 = *(const float4*)(Li + lr * 128 + kb + k8 + 4);
      float4 cv = *(const float4*)(E + (size_t)(k + kb + kk) * NDIM + c0 + c4);
      __syncthreads();
      Ls[(k8 + 0) * 128 + lr] = l0.x; Ls[(k8 + 1) * 128 + lr] = l0.y;
      Ls[(k8 + 2) * 128 + lr] = l0.z; Ls[(k8 + 3) * 128 + lr] = l0.w;
      Ls[(k8 + 4) * 128 + lr] = l1.x; Ls[(k8 + 5) * 128 + lr] = l1.y;
      Ls[(k8 + 6) * 128 + lr] = l1.z; Ls[(k8 + 7) * 128 + lr] = l1.w;
      *(float4*)&Cs[kk * 64 + c4] = cv;
      __syncthreads();
#pragma unroll
      for (int k2 = 0; k2 < 16; ++k2) {
        float ra[8], rb[4];
#pragma unroll
        for (int r = 0; r < 8; ++r) ra[r] = Ls[k2 * 128 + ty * 8 + r];
#pragma unroll
        for (int c = 0; c < 4; ++c) rb[c] = Cs[k2 * 64 + tx * 4 + c];
#pragma unroll
        for (int r = 0; r < 8; ++r)
#pragma unroll
          for (int c = 0; c < 4; ++c) acc[r][c] += ra[r] * rb[c];
      }
    }
#pragma unroll
    for (int r = 0; r < 8; ++r) {
      float4 v = {acc[r][0], acc[r][1], acc[r][2], acc[r][3]};
      *(float4*)(E + (size_t)(k + ty * 8 + r) * NDIM + c0 + tx * 4) = v;
    }
  }
}

// ==================== trailing update E22 -= L21*U12 (pure GEMM) ==========
__global__ __launch_bounds__(512) void lu_update128(float* __restrict__ E, int k) {
  __shared__ float As[2][16][128];
  __shared__ float Bs[2][16][128];
  const int t = threadIdx.x;
  const int tx = t & 31, ty = t >> 5;
  const int lr = t >> 2, lk = (t & 3) * 4;
  const int i0 = k + 128 + blockIdx.y * 128;
  const int j0 = k + 128 + blockIdx.x * 128;
  const float* Ap = E + (size_t)(i0 + lr) * NDIM + k + lk;
  const float* Bp = E + (size_t)(k + ty) * NDIM + j0 + tx * 4;
  float acc[8][4];
#pragma unroll
  for (int r = 0; r < 8; ++r)
#pragma unroll
    for (int c = 0; c < 4; ++c) acc[r][c] = 0.f;
  {
    float4 a = *(const float4*)Ap;
    float4 b = *(const float4*)Bp;
    As[0][lk + 0][lr] = a.x; As[0][lk + 1][lr] = a.y;
    As[0][lk + 2][lr] = a.z; As[0][lk + 3][lr] = a.w;
    *(float4*)&Bs[0][ty][tx * 4] = b;
  }
  int cur = 0;
  for (int k0 = 16;; k0 += 16) {
    const bool more = k0 < 128;
    float4 na, nb;
    if (more) {
      na = *(const float4*)(Ap + k0);
      nb = *(const float4*)(Bp + (size_t)k0 * NDIM);
    }
    __syncthreads();
#pragma unroll
    for (int kk = 0; kk < 16; ++kk) {
      float ra[8], rb[4];
#pragma unroll
      for (int r = 0; r < 8; ++r) ra[r] = As[cur][kk][ty * 8 + r];
#pragma unroll
      for (int c = 0; c < 4; ++c) rb[c] = Bs[cur][kk][tx * 4 + c];
#pragma unroll
      for (int r = 0; r < 8; ++r)
#pragma unroll
        for (int c = 0; c < 4; ++c) acc[r][c] += ra[r] * rb[c];
    }
    if (!more) break;
    const int nx = cur ^ 1;
    As[nx][lk + 0][lr] = na.x; As[nx][lk + 1][lr] = na.y;
    As[nx][lk + 2][lr] = na.z; As[nx][lk + 3][lr] = na.w;
    *(float4*)&Bs[nx][ty][tx * 4] = nb;
    cur = nx;
  }
#pragma unroll
  for (int r = 0; r < 8; ++r) {
    float* p = E + (size_t)(i0 + ty * 8 + r) * NDIM + j0 + tx * 4;
    float4 o = *(const float4*)p;
    float4 v = {o.x - acc[r][0], o.y - acc[r][1], o.z - acc[r][2], o.w - acc[r][3]};
    *(float4*)p = v;
  }
}

// ==================== left-looking solve slab =============================
// Slab rows [i0,i0+128). T = F_i - sum_{kb in [kb0,kb1)} E[i-rows][kb]*F[kb rows],
// then F_i = Inv(128x128) * T. 64 blocks of 32-col stripes, 256 threads.
__global__ __launch_bounds__(256) void solve_slab(const float* __restrict__ E,
                                                  float* __restrict__ F,
                                                  const float* __restrict__ Inv,
                                                  int i0, int kb0, int kb1) {
  __shared__ float sh[9344];
  float* As = sh;          // [2][16][128] = 4096
  float* Bs = sh + 4096;   // [2][16][32]  = 1024
  float* Tl = sh + 5120;   // [128][33]    = 4224
  float* Ls = sh;          // alias (staging dead by then)
  const int t = threadIdx.x;
  const int j0 = (int)blockIdx.x * 32;
  const int ty = t >> 3, tx = t & 7;          // 4 rows x 4 cols per thread
  const int lr = t >> 1, k8 = (t & 1) * 8;    // A/Ls stage
  const int bkk = t >> 4, bc2 = (t & 15) * 2; // B stage
  float acc[4][4];
#pragma unroll
  for (int r = 0; r < 4; ++r)
#pragma unroll
    for (int c = 0; c < 4; ++c) acc[r][c] = 0.f;

  if (kb1 > kb0) {
    {
      float4 a0 = *(const float4*)(E + (size_t)(i0 + lr) * NDIM + kb0 + k8);
      float4 a1 = *(const float4*)(E + (size_t)(i0 + lr) * NDIM + kb0 + k8 + 4);
      float2 b0 = *(const float2*)(F + (size_t)(kb0 + bkk) * NDIM + j0 + bc2);
      As[(k8 + 0) * 128 + lr] = a0.x; As[(k8 + 1) * 128 + lr] = a0.y;
      As[(k8 + 2) * 128 + lr] = a0.z; As[(k8 + 3) * 128 + lr] = a0.w;
      As[(k8 + 4) * 128 + lr] = a1.x; As[(k8 + 5) * 128 + lr] = a1.y;
      As[(k8 + 6) * 128 + lr] = a1.z; As[(k8 + 7) * 128 + lr] = a1.w;
      Bs[bkk * 32 + bc2] = b0.x; Bs[bkk * 32 + bc2 + 1] = b0.y;
    }
    int cur = 0;
    for (int kb = kb0 + 16;; kb += 16) {
      const bool more = kb < kb1;
      float4 na0, na1; float2 nb0;
      if (more) {
        na0 = *(const float4*)(E + (size_t)(i0 + lr) * NDIM + kb + k8);
        na1 = *(const float4*)(E + (size_t)(i0 + lr) * NDIM + kb + k8 + 4);
        nb0 = *(const float2*)(F + (size_t)(kb + bkk) * NDIM + j0 + bc2);
      }
      __syncthreads();
#pragma unroll
      for (int kk = 0; kk < 16; ++kk) {
        float ra[4], rb[4];
#pragma unroll
        for (int r = 0; r < 4; ++r) ra[r] = As[cur * 2048 + kk * 128 + ty * 4 + r];
#pragma unroll
        for (int c = 0; c < 4; ++c) rb[c] = Bs[cur * 512 + kk * 32 + tx * 4 + c];
#pragma unroll
        for (int r = 0; r < 4; ++r)
#pragma unroll
          for (int c = 0; c < 4; ++c) acc[r][c] += ra[r] * rb[c];
      }
      if (!more) break;
      const int nx = cur ^ 1;
      As[nx * 2048 + (k8 + 0) * 128 + lr] = na0.x; As[nx * 2048 + (k8 + 1) * 128 + lr] = na0.y;
      As[nx * 2048 + (k8 + 2) * 128 + lr] = na0.z; As[nx * 2048 + (k8 + 3) * 128 + lr] = na0.w;
      As[nx * 2048 + (k8 + 4) * 128 + lr] = na1.x; As[nx * 2048 + (k8 + 5) * 128 + lr] = na1.y;
      As[nx * 2048 + (k8 + 6) * 128 + lr] = na1.z; As[nx * 2048 + (k8 + 7) * 128 + lr] = na1.w;
      Bs[nx * 512 + bkk * 32 + bc2] = nb0.x; Bs[nx * 512 + bkk * 32 + bc2 + 1] = nb0.y;
      cur = nx;
    }
  }
  __syncthreads();
  // T = F_i - acc -> Tl
#pragma unroll
  for (int r = 0; r < 4; ++r) {
    float4 f = *(const float4*)(F + (size_t)(i0 + ty * 4 + r) * NDIM + j0 + tx * 4);
    Tl[(ty * 4 + r) * 33 + tx * 4 + 0] = f.x - acc[r][0];
    Tl[(ty * 4 + r) * 33 + tx * 4 + 1] = f.y - acc[r][1];
    Tl[(ty * 4 + r) * 33 + tx * 4 + 2] = f.z - acc[r][2];
    Tl[(ty * 4 + r) * 33 + tx * 4 + 3] = f.w - acc[r][3];
  }
  __syncthreads();
  // Y = Inv * T
  float a2[4][4];
#pragma unroll
  for (int r = 0; r < 4; ++r)
#pragma unroll
    for (int c = 0; c < 4; ++c) a2[r][c] = 0.f;
  for (int kb = 0; kb < 128; kb += 16) {
    __syncthreads();
    {
      float4 l0 = *(const float4*)(Inv + lr * 128 + kb + k8);
      float4 l1 = *(const float4*)(Inv + lr * 128 + kb + k8 + 4);
      Ls[(k8 + 0) * 128 + lr] = l0.x; Ls[(k8 + 1) * 128 + lr] = l0.y;
      Ls[(k8 + 2) * 128 + lr] = l0.z; Ls[(k8 + 3) * 128 + lr] = l0.w;
      Ls[(k8 + 4) * 128 + lr] = l1.x; Ls[(k8 + 5) * 128 + lr] = l1.y;
      Ls[(k8 + 6) * 128 + lr] = l1.z; Ls[(k8 + 7) * 128 + lr] = l1.w;
    }
    __syncthreads();
#pragma unroll
    for (int kk = 0; kk < 16; ++kk) {
      float ra[4], rb[4];
#pragma unroll
      for (int r = 0; r < 4; ++r) ra[r] = Ls[kk * 128 + ty * 4 + r];
#pragma unroll
      for (int c = 0; c < 4; ++c) rb[c] = Tl[(kb + kk) * 33 + tx * 4 + c];
#pragma unroll
      for (int r = 0; r < 4; ++r)
#pragma unroll
        for (int c = 0; c < 4; ++c) a2[r][c] += ra[r] * rb[c];
    }
  }
#pragma unroll
  for (int r = 0; r < 4; ++r) {
    float4 v = {a2[r][0], a2[r][1], a2[r][2], a2[r][3]};
    *(float4*)(F + (size_t)(i0 + ty * 4 + r) * NDIM + j0 + tx * 4) = v;
  }
}

extern "C" void kernel_launch(void* const* d_in, const int* in_sizes, int n_in,
                              void* d_out, int out_size, void* d_ws, size_t ws_size,
                              hipStream_t stream) {
  const float* L = (const float*)d_in[0];
  const float* R = (const float*)d_in[1];
  const float* Bin = (const float*)d_in[2];

  float* ws = (float*)d_ws;
  float* P = ws;                          // 2048^2
  float* F = ws + (size_t)NN;             // 2048^2: F -> Y -> Acl -> A
  float* C1 = ws + (size_t)2 * NN;        // 256 x 2048
  float* W = C1 + (size_t)256 * NDIM;     // 256 x 2048
  float* Linv = W + (size_t)256 * NDIM;   // 16 x 128 x 128
  float* Uinv = Linv + (size_t)16 * 16384;
  float* E = (float*)d_out;               // LU factors live in d_out until the end

  const float* L1 = L;
  const float* L2 = L + (size_t)NDIM * KDIM;

  dim3 g16(16, 16);
  gemm_nt_big<<<g16, 512, 0, stream>>>(L2, L2, P);
  gemm_nt_big<<<g16, 512, 0, stream>>>(L2, L1, F);
  gemm_nt_big<<<g16, 512, 0, stream>>>(L1, L1, E);
  make_E<<<dim3(32, 32), 256, 0, stream>>>(E, P, R);

  // ---- LU (no pivoting), NB=128, panels via diag-block inverses
  for (int k = 0; k < NDIM; k += 128) {
    const int idx = k >> 7;
    lu_diag128<<<1, 512, 0, stream>>>(E, k);
    tri_inv128<<<1, 256, 0, stream>>>(E, k, Linv + (size_t)idx * 16384,
                                      Uinv + (size_t)idx * 16384);
    const int rem = NDIM - k - 128;
    if (rem > 0) {
      const int nb = rem / 64;
      lu_panels_inv<<<2 * nb, 256, 0, stream>>>(E, k, Linv + (size_t)idx * 16384,
                                                Uinv + (size_t)idx * 16384, nb);
      lu_update128<<<dim3(rem / 128, rem / 128), 512, 0, stream>>>(E, k);
    }
  }

  // ---- forward solve L Y = F (left-looking slabs)
  for (int i = 0; i < 16; ++i)
    solve_slab<<<64, 256, 0, stream>>>(E, F, Linv + (size_t)i * 16384, i * 128, 0,
                                       i * 128);
  // ---- backward solve U X = Y
  for (int i = 15; i >= 0; --i)
    solve_slab<<<64, 256, 0, stream>>>(E, F, Uinv + (size_t)i * 16384, i * 128,
                                       (i + 1) * 128, NDIM);

  // ---- A = (I - B (B^T P)) Acl
  gemm_tile64<true><<<dim3(32, 4), 256, 0, stream>>>(Bin, P, C1, 256, NDIM, NDIM,
                                                     256, NDIM, NDIM, 1.f, 0.f);
  gemm_tile64<false><<<dim3(32, 4), 256, 0, stream>>>(C1, F, W, 256, NDIM, NDIM,
                                                      NDIM, NDIM, NDIM, 1.f, 0.f);
  gemm_tile64<false><<<dim3(32, 32), 256, 0, stream>>>(Bin, W, F, NDIM, NDIM, 256,
                                                       256, NDIM, NDIM, -1.f, 1.f);
  hipMemcpyAsync(d_out, F, (size_t)NN * sizeof(float), hipMemcpyDeviceToDevice,
                 stream);
}